// Round 4
// baseline (706.363 us; speedup 1.0000x reference)
//
#include <hip/hip_runtime.h>
#include <hip/hip_bf16.h>

// Problem constants (T,K,E,H,I) = (1024, 2, 8, 2048, 1024)
#define T_TOK 1024
#define KSEL  2
#define NEXP  8
#define HDIM  2048
#define IDIM  1024
#define TK    (T_TOK * KSEL)   // 2048 (token, slot) pairs

#define BK 64   // K-slab depth in bf16 elements
#define RS 72   // LDS row stride in bf16 elems (64 payload + 8 pad = 144 B)
                // 144B stride: each 8-lane phase of a b128 op covers all 32 banks.

typedef float  f32x4  __attribute__((ext_vector_type(4)));
typedef __bf16 bf16x8 __attribute__((ext_vector_type(8)));
typedef __bf16 bf16x2 __attribute__((ext_vector_type(2)));

__device__ __forceinline__ unsigned short f2bf(float f) {
    union { float f; unsigned u; } v; v.f = f;
    unsigned r = (v.u >> 16) & 1u;               // round-to-nearest-even
    return (unsigned short)((v.u + 0x7fffu + r) >> 16);
}

__device__ __forceinline__ unsigned pk2bf(float lo, float hi) {
#if __has_builtin(__builtin_amdgcn_cvt_pk_bf16_f32)
    bf16x2 v = __builtin_amdgcn_cvt_pk_bf16_f32(lo, hi);
    union { bf16x2 v; unsigned u; } c; c.v = v;
    return c.u;
#else
    return (unsigned)f2bf(lo) | ((unsigned)f2bf(hi) << 16);
#endif
}

// ---------------------------------------------------------------------------
// Kernel 0: bucket the 2048 (t,k) pairs by expert (counting sort, 1 block).
// ---------------------------------------------------------------------------
__global__ void build_pairs(const int* __restrict__ sel, int* __restrict__ meta,
                            int* __restrict__ pairs) {
    __shared__ int lcnt[NEXP], lstart[NEXP], lfill[NEXP];
    const int tid = threadIdx.x;
    if (tid < NEXP) { lcnt[tid] = 0; lfill[tid] = 0; }
    __syncthreads();
    for (int idx = tid; idx < TK; idx += 256) atomicAdd(&lcnt[sel[idx]], 1);
    __syncthreads();
    if (tid == 0) {
        int s = 0;
        for (int e = 0; e < NEXP; ++e) { lstart[e] = s; s += lcnt[e]; }
    }
    __syncthreads();
    for (int idx = tid; idx < TK; idx += 256) {
        int e = sel[idx];
        int pos = lstart[e] + atomicAdd(&lfill[e], 1);
        pairs[pos] = idx;
    }
    if (tid < NEXP) { meta[tid] = lcnt[tid]; meta[NEXP + tid] = lstart[tid]; }
}

// ---------------------------------------------------------------------------
// Kernel 1: stream-convert gup / down / hidden fp32 -> bf16 workspace copies.
// 6,553,600 chunks of 8 floats; grid 6400x256 -> exactly 4 chunks/thread.
// ---------------------------------------------------------------------------
__global__ __launch_bounds__(256) void cvt_all(
    const float* __restrict__ gup, const float* __restrict__ down,
    const float* __restrict__ hidden, unsigned short* __restrict__ gup_bf,
    unsigned short* __restrict__ down_bf, unsigned short* __restrict__ hid_bf)
{
    const long NG = (long)NEXP * 2 * IDIM * HDIM / 8;   // 4,194,304
    const long ND = (long)NEXP * HDIM * IDIM / 8;       // 2,097,152
    const long NH = (long)T_TOK * HDIM / 8;             //   262,144
    const long NT = NG + ND + NH;
    for (long i = (long)blockIdx.x * 256 + threadIdx.x; i < NT;
         i += (long)gridDim.x * 256) {
        const float* s; unsigned short* d; long c;
        if (i < NG)           { s = gup;    d = gup_bf;  c = i; }
        else if (i < NG + ND) { s = down;   d = down_bf; c = i - NG; }
        else                  { s = hidden; d = hid_bf;  c = i - NG - ND; }
        float4 v0 = *(const float4*)(s + c * 8);
        float4 v1 = *(const float4*)(s + c * 8 + 4);
        uint4 o;
        o.x = pk2bf(v0.x, v0.y); o.y = pk2bf(v0.z, v0.w);
        o.z = pk2bf(v1.x, v1.y); o.w = pk2bf(v1.z, v1.w);
        *(uint4*)(d + c * 8) = o;
    }
}

// ---------------------------------------------------------------------------
// Kernel 2: gate_up GEMM + SiLU*up -> bf16 intermediate. All-bf16 inputs.
// Tile M64 x N32 (B rows: 32 gate + 32 up), BK=64, depth-3 pipeline.
// bx = ((nt*32 + mt)*8 + e): expert -> XCD swizzle; 4 mt-blocks of one
// (nt,e) tile are bx%8-equal and adjacent -> same XCD L2 serves re-reads.
// Active blocks ~ 4(mt) x 32(nt) x 8(e) = 1024 = 4/CU.
// ---------------------------------------------------------------------------
__global__ __launch_bounds__(256, 4) void gemm1_gateup(
    const unsigned short* __restrict__ hid_bf, const unsigned short* __restrict__ gup_bf,
    const int* __restrict__ meta, const int* __restrict__ pairs,
    unsigned short* __restrict__ inter)
{
    __shared__ __align__(16) unsigned short As[2][64 * RS];
    __shared__ __align__(16) unsigned short Bs[2][64 * RS];

    const int bx = blockIdx.x;
    const int e = bx & 7, mt = (bx >> 3) & 31, nt = bx >> 8;
    const int cnt = meta[e];
    const int m0 = mt * 64;
    if (m0 >= cnt) return;
    const int seg  = meta[8 + e];
    const int rows = min(64, cnt - m0);
    const int n0   = nt * 32;

    const int tid  = threadIdx.x;
    const int lane = tid & 63, wave = tid >> 6;
    const int quad = lane >> 4, l16 = lane & 15;
    const int wm = wave >> 1, wn = wave & 1;

    const unsigned short* __restrict__ Wb = gup_bf + (size_t)e * (2 * IDIM * HDIM);

    // A: 64 rows x 64 k = 512 16B-chunks; 2 per thread. Clamp row -> rows-1
    // (dup data; results for rows >= `rows` discarded in epilogue).
    const unsigned short* aptr[2]; int aofs[2];
    #pragma unroll
    for (int c = 0; c < 2; ++c) {
        int id = tid + c * 256;
        int row = id >> 3, kc = (id & 7) * 8;
        int ar = min(row, rows - 1);
        int tok = pairs[seg + m0 + ar] >> 1;
        aptr[c] = hid_bf + (size_t)tok * HDIM + kc;
        aofs[c] = row * RS + kc;
    }
    // B: rows 0..31 = gate rows n0+r; rows 32..63 = up rows IDIM+n0+(r-32).
    const unsigned short* bptr[2]; int bofs[2];
    #pragma unroll
    for (int c = 0; c < 2; ++c) {
        int id = tid + c * 256;
        int row = id >> 3, kc = (id & 7) * 8;
        int gr = (row < 32) ? (n0 + row) : (IDIM + n0 + (row - 32));
        bptr[c] = Wb + (size_t)gr * HDIM + kc;
        bofs[c] = row * RS + kc;
    }

    f32x4 accg[2], accu[2];
    const f32x4 zero = {0.f, 0.f, 0.f, 0.f};
    accg[0] = zero; accg[1] = zero; accu[0] = zero; accu[1] = zero;

    uint4 Qa0[2], Qb0[2], Qa1[2], Qb1[2];
    auto load0 = [&](int k0) {
        #pragma unroll
        for (int c = 0; c < 2; ++c) { Qa0[c] = *(const uint4*)(aptr[c] + k0);
                                      Qb0[c] = *(const uint4*)(bptr[c] + k0); }
    };
    auto load1 = [&](int k0) {
        #pragma unroll
        for (int c = 0; c < 2; ++c) { Qa1[c] = *(const uint4*)(aptr[c] + k0);
                                      Qb1[c] = *(const uint4*)(bptr[c] + k0); }
    };
    auto store0 = [&](int buf) {
        #pragma unroll
        for (int c = 0; c < 2; ++c) { *(uint4*)&As[buf][aofs[c]] = Qa0[c];
                                      *(uint4*)&Bs[buf][bofs[c]] = Qb0[c]; }
    };
    auto store1 = [&](int buf) {
        #pragma unroll
        for (int c = 0; c < 2; ++c) { *(uint4*)&As[buf][aofs[c]] = Qa1[c];
                                      *(uint4*)&Bs[buf][bofs[c]] = Qb1[c]; }
    };
    auto compute = [&](int buf) {
        #pragma unroll
        for (int ks = 0; ks < 2; ++ks) {
            const int kq = ks * 32 + quad * 8;
            bf16x8 af0 = *(const bf16x8*)&As[buf][(wm * 32 + l16) * RS + kq];
            bf16x8 af1 = *(const bf16x8*)&As[buf][(wm * 32 + 16 + l16) * RS + kq];
            bf16x8 bg  = *(const bf16x8*)&Bs[buf][(wn * 16 + l16) * RS + kq];
            bf16x8 bu  = *(const bf16x8*)&Bs[buf][(32 + wn * 16 + l16) * RS + kq];
            accg[0] = __builtin_amdgcn_mfma_f32_16x16x32_bf16(af0, bg, accg[0], 0, 0, 0);
            accg[1] = __builtin_amdgcn_mfma_f32_16x16x32_bf16(af1, bg, accg[1], 0, 0, 0);
            accu[0] = __builtin_amdgcn_mfma_f32_16x16x32_bf16(af0, bu, accu[0], 0, 0, 0);
            accu[1] = __builtin_amdgcn_mfma_f32_16x16x32_bf16(af1, bu, accu[1], 0, 0, 0);
        }
    };

    const int NK = HDIM / BK;   // 32
    load0(0);
    store0(0);
    load1(BK);
    load0(2 * BK);
    __syncthreads();
    for (int k = 0; ; k += 2) {
        compute(0);
        store1(1);
        if (k + 3 < NK) load1((k + 3) * BK);
        __syncthreads();
        compute(1);
        if (k + 2 >= NK) break;
        store0(0);
        if (k + 4 < NK) load0((k + 4) * BK);
        __syncthreads();
    }

    #pragma unroll
    for (int i = 0; i < 2; ++i) {
        #pragma unroll
        for (int r = 0; r < 4; ++r) {
            int ml = wm * 32 + i * 16 + quad * 4 + r;
            if (ml < rows) {
                size_t orow = (size_t)(seg + m0 + ml) * IDIM;
                int n = n0 + wn * 16 + l16;
                float g = (i == 0) ? accg[0][r] : accg[1][r];
                float u = (i == 0) ? accu[0][r] : accu[1][r];
                float s = g * (1.f / (1.f + __expf(-g)));
                inter[orow + n] = f2bf(s * u);
            }
        }
    }
}

// ---------------------------------------------------------------------------
// Kernel 3: down-proj GEMM, all-bf16 inputs, fp32 scattered output.
// Tile M64 x N64, BK=64, NK=16, depth-3 pipeline, expert->XCD swizzle.
// ---------------------------------------------------------------------------
__global__ __launch_bounds__(256, 4) void gemm2_down(
    const unsigned short* __restrict__ inter, const unsigned short* __restrict__ down_bf,
    const int* __restrict__ meta, const int* __restrict__ pairs,
    float* __restrict__ out)
{
    __shared__ __align__(16) unsigned short As[2][64 * RS];
    __shared__ __align__(16) unsigned short Bs[2][64 * RS];

    const int bx = blockIdx.x;
    const int e = bx & 7, mt = (bx >> 3) & 31, nt = bx >> 8;
    const int cnt = meta[e];
    const int m0 = mt * 64;
    if (m0 >= cnt) return;
    const int seg  = meta[8 + e];
    const int rows = min(64, cnt - m0);
    const int n0   = nt * 64;

    const int tid  = threadIdx.x;
    const int lane = tid & 63, wave = tid >> 6;
    const int quad = lane >> 4, l16 = lane & 15;
    const int wm = wave >> 1, wn = wave & 1;

    const unsigned short* __restrict__ Db = down_bf + (size_t)e * (HDIM * IDIM);

    const unsigned short* aptr[2]; int aofs[2];
    #pragma unroll
    for (int c = 0; c < 2; ++c) {
        int id = tid + c * 256;
        int row = id >> 3, kc = (id & 7) * 8;
        int ar = min(row, rows - 1);
        aptr[c] = inter + (size_t)(seg + m0 + ar) * IDIM + kc;
        aofs[c] = row * RS + kc;
    }
    const unsigned short* bptr[2]; int bofs[2];
    #pragma unroll
    for (int c = 0; c < 2; ++c) {
        int id = tid + c * 256;
        int row = id >> 3, kc = (id & 7) * 8;
        bptr[c] = Db + (size_t)(n0 + row) * IDIM + kc;
        bofs[c] = row * RS + kc;
    }

    f32x4 acc[2][2];
    const f32x4 zero = {0.f, 0.f, 0.f, 0.f};
    acc[0][0] = zero; acc[0][1] = zero; acc[1][0] = zero; acc[1][1] = zero;

    uint4 Qa0[2], Qb0[2], Qa1[2], Qb1[2];
    auto load0 = [&](int k0) {
        #pragma unroll
        for (int c = 0; c < 2; ++c) { Qa0[c] = *(const uint4*)(aptr[c] + k0);
                                      Qb0[c] = *(const uint4*)(bptr[c] + k0); }
    };
    auto load1 = [&](int k0) {
        #pragma unroll
        for (int c = 0; c < 2; ++c) { Qa1[c] = *(const uint4*)(aptr[c] + k0);
                                      Qb1[c] = *(const uint4*)(bptr[c] + k0); }
    };
    auto store0 = [&](int buf) {
        #pragma unroll
        for (int c = 0; c < 2; ++c) { *(uint4*)&As[buf][aofs[c]] = Qa0[c];
                                      *(uint4*)&Bs[buf][bofs[c]] = Qb0[c]; }
    };
    auto store1 = [&](int buf) {
        #pragma unroll
        for (int c = 0; c < 2; ++c) { *(uint4*)&As[buf][aofs[c]] = Qa1[c];
                                      *(uint4*)&Bs[buf][bofs[c]] = Qb1[c]; }
    };
    auto compute = [&](int buf) {
        #pragma unroll
        for (int ks = 0; ks < 2; ++ks) {
            const int kq = ks * 32 + quad * 8;
            bf16x8 af0 = *(const bf16x8*)&As[buf][(wm * 32 + l16) * RS + kq];
            bf16x8 af1 = *(const bf16x8*)&As[buf][(wm * 32 + 16 + l16) * RS + kq];
            bf16x8 bf0 = *(const bf16x8*)&Bs[buf][(wn * 32 + l16) * RS + kq];
            bf16x8 bf1 = *(const bf16x8*)&Bs[buf][(wn * 32 + 16 + l16) * RS + kq];
            acc[0][0] = __builtin_amdgcn_mfma_f32_16x16x32_bf16(af0, bf0, acc[0][0], 0, 0, 0);
            acc[0][1] = __builtin_amdgcn_mfma_f32_16x16x32_bf16(af0, bf1, acc[0][1], 0, 0, 0);
            acc[1][0] = __builtin_amdgcn_mfma_f32_16x16x32_bf16(af1, bf0, acc[1][0], 0, 0, 0);
            acc[1][1] = __builtin_amdgcn_mfma_f32_16x16x32_bf16(af1, bf1, acc[1][1], 0, 0, 0);
        }
    };

    const int NK = IDIM / BK;   // 16
    load0(0);
    store0(0);
    load1(BK);
    load0(2 * BK);
    __syncthreads();
    for (int k = 0; ; k += 2) {
        compute(0);
        store1(1);
        if (k + 3 < NK) load1((k + 3) * BK);
        __syncthreads();
        compute(1);
        if (k + 2 >= NK) break;
        store0(0);
        if (k + 4 < NK) load0((k + 4) * BK);
        __syncthreads();
    }

    #pragma unroll
    for (int i = 0; i < 2; ++i) {
        #pragma unroll
        for (int r = 0; r < 4; ++r) {
            int ml = wm * 32 + i * 16 + quad * 4 + r;
            if (ml < rows) {
                int p = pairs[seg + m0 + ml];
                size_t ob = (size_t)p * HDIM + n0 + wn * 32 + l16;
                out[ob]      = acc[i][0][r];
                out[ob + 16] = acc[i][1][r];
            }
        }
    }
}

// ---------------------------------------------------------------------------
extern "C" void kernel_launch(void* const* d_in, const int* in_sizes, int n_in,
                              void* d_out, int out_size, void* d_ws, size_t ws_size,
                              hipStream_t stream) {
    const float* hidden = (const float*)d_in[0];   // (T, H) fp32
    const int*   sel    = (const int*)  d_in[1];   // (T, K) int32
    const float* gup    = (const float*)d_in[2];   // (E, 2I, H) fp32
    const float* down   = (const float*)d_in[3];   // (E, H, I) fp32
    float* out = (float*)d_out;                    // (T, K, H) fp32

    // ws layout (bytes):
    //   [0)        meta: 16 ints
    //   [64)       pairs: 2048 ints
    //   [16384)            inter   bf16 2048x1024   ( 4 MB)
    //   [16384+4M)         gup_bf  bf16 8x2048x2048 (64 MB)
    //   [+64M)             down_bf bf16 8x2048x1024 (32 MB)
    //   [+32M)             hid_bf  bf16 1024x2048   ( 4 MB)   total ~104 MB
    char* ws = (char*)d_ws;
    int* meta  = (int*)ws;
    int* pairs = meta + 16;
    unsigned short* inter   = (unsigned short*)(ws + 16384);
    unsigned short* gup_bf  = inter + (size_t)TK * IDIM;
    unsigned short* down_bf = gup_bf + (size_t)NEXP * 2 * IDIM * HDIM;
    unsigned short* hid_bf  = down_bf + (size_t)NEXP * HDIM * IDIM;

    build_pairs<<<1, 256, 0, stream>>>(sel, meta, pairs);
    cvt_all<<<6400, 256, 0, stream>>>(gup, down, hidden, gup_bf, down_bf, hid_bf);
    gemm1_gateup<<<8192, 256, 0, stream>>>(hid_bf, gup_bf, meta, pairs, inter);
    gemm2_down  <<<8192, 256, 0, stream>>>(inter, down_bf, meta, pairs, out);
}

// Round 6
// 285.631 us; speedup vs baseline: 2.4730x; 2.4730x over previous
//
#include <hip/hip_runtime.h>
#include <hip/hip_bf16.h>

// Problem constants (T,K,E,H,I) = (1024, 2, 8, 2048, 1024)
#define T_TOK 1024
#define KSEL  2
#define NEXP  8
#define HDIM  2048
#define IDIM  1024
#define TK    2048            // (token, slot) pairs; sum of expert counts == TK

#define BR 72                 // LDS B-tile row stride in bf16 elems (64 payload + 8 pad)
#define MT 3                  // M-tiles per expert (384 rows each); mt>0 inactive unless cnt>384

typedef float  f32x4  __attribute__((ext_vector_type(4)));
typedef __bf16 bf16x8 __attribute__((ext_vector_type(8)));
typedef __bf16 bf16x2 __attribute__((ext_vector_type(2)));

__device__ __forceinline__ unsigned short f2bf(float f) {
    union { float f; unsigned u; } v; v.f = f;
    unsigned r = (v.u >> 16) & 1u;               // round-to-nearest-even
    return (unsigned short)((v.u + 0x7fffu + r) >> 16);
}

__device__ __forceinline__ unsigned pk2bf(float lo, float hi) {
#if __has_builtin(__builtin_amdgcn_cvt_pk_bf16_f32)
    bf16x2 v = __builtin_amdgcn_cvt_pk_bf16_f32(lo, hi);
    union { bf16x2 v; unsigned u; } c; c.v = v;
    return c.u;
#else
    return (unsigned)f2bf(lo) | ((unsigned)f2bf(hi) << 16);
#endif
}

// ---------------------------------------------------------------------------
// Kernel 1: prep = hidden fp32->bf16 (all blocks) + expert counting-sort
// (block 0 only). Grid 1024 x 256 covers T*H/8 = 262144 chunks exactly.
// ---------------------------------------------------------------------------
__global__ __launch_bounds__(256) void prep(
    const float* __restrict__ hidden, const int* __restrict__ sel,
    unsigned short* __restrict__ hid_bf, int* __restrict__ meta,
    int* __restrict__ pairs)
{
    const int t = blockIdx.x * 256 + threadIdx.x;
    {
        const float* s = hidden + (size_t)t * 8;
        float4 v0 = *(const float4*)s;
        float4 v1 = *(const float4*)(s + 4);
        uint4 o;
        o.x = pk2bf(v0.x, v0.y); o.y = pk2bf(v0.z, v0.w);
        o.z = pk2bf(v1.x, v1.y); o.w = pk2bf(v1.z, v1.w);
        *(uint4*)(hid_bf + (size_t)t * 8) = o;
    }
    if (blockIdx.x == 0) {
        __shared__ int lcnt[NEXP], lstart[NEXP], lfill[NEXP];
        const int tid = threadIdx.x;
        if (tid < NEXP) { lcnt[tid] = 0; lfill[tid] = 0; }
        __syncthreads();
        for (int i = tid; i < TK; i += 256) atomicAdd(&lcnt[sel[i]], 1);
        __syncthreads();
        if (tid == 0) {
            int s2 = 0;
            for (int e2 = 0; e2 < NEXP; ++e2) { lstart[e2] = s2; s2 += lcnt[e2]; }
        }
        __syncthreads();
        for (int i = tid; i < TK; i += 256) {
            int e2 = sel[i];
            pairs[lstart[e2] + atomicAdd(&lfill[e2], 1)] = i;   // i == t*K+k
        }
        if (tid < NEXP) { meta[tid] = lcnt[tid]; meta[NEXP + tid] = lstart[tid]; }
    }
}

// ---------------------------------------------------------------------------
// Kernel 2: gate_up GEMM + SiLU*up -> bf16 inter (packed rows).
// Block = 512 threads = 8 waves; wave w owns M rows [48w, 48w+48) -> 384 rows
// = full expert. N = 32 inter cols (64 weight rows: 32 gate + 32 up).
// B fp32 streamed once from HBM -> cvt in-reg -> LDS (triple-buffer, one
// barrier per slab-half, 2-slab register prefetch). A read directly from
// global (16 full 64B lines per b128 wave-load; XCD-local L2 hits, e=bx&7
// pins expert->XCD). K-slab 64, NK=32.
// ---------------------------------------------------------------------------
__global__ __launch_bounds__(512, 2) void gemm1_gateup(
    const unsigned short* __restrict__ hid_bf, const float* __restrict__ gup,
    const int* __restrict__ meta, const int* __restrict__ pairs,
    unsigned short* __restrict__ inter)
{
    __shared__ __align__(16) unsigned short Bs[3][64 * BR];

    const int bx = blockIdx.x;
    const int e = bx & 7, nt = (bx >> 3) & 31, mt = bx >> 8;
    const int cnt = meta[e];
    const int m0 = mt * 384;
    if (m0 >= cnt) return;
    const int seg  = meta[8 + e];
    const int rows = cnt - m0;            // valid rows in this tile
    const int n0   = nt * 32;

    const int tid  = threadIdx.x;
    const int lane = tid & 63, w = tid >> 6;        // w in [0,8)
    const int quad = lane >> 4, l16 = lane & 15;

    // B staging map (512 thr): thread = weight-row (tid>>3), k-chunk (tid&7)*8.
    const int brow = tid >> 3, bkc = (tid & 7) * 8;
    const int grow = (brow < 32) ? (n0 + brow) : (IDIM + n0 + (brow - 32));
    const float* __restrict__ bp =
        gup + (size_t)e * (2 * IDIM * HDIM) + (size_t)grow * HDIM + bkc;
    const int bofs = brow * BR + bkc;

    // A fragment base pointers: 3 m-tiles of 16 rows, lane row = l16.
    const unsigned short* ap[3];
    #pragma unroll
    for (int i = 0; i < 3; ++i) {
        int mr  = m0 + w * 48 + i * 16 + l16;
        int idx = seg + min(mr, cnt - 1);          // clamp (dup rows masked later)
        ap[i] = hid_bf + (size_t)(pairs[idx] >> 1) * HDIM + quad * 8;
    }

    f32x4 accg[3][2], accu[3][2];
    const f32x4 zero = {0.f, 0.f, 0.f, 0.f};
    #pragma unroll
    for (int i = 0; i < 3; ++i)
        #pragma unroll
        for (int j = 0; j < 2; ++j) { accg[i][j] = zero; accu[i][j] = zero; }

    float4 Br0[2], Br1[2];
    bf16x8 afA[3][2], afB[3][2];

    auto loadB = [&](float4 (&br)[2], int s) {
        const float* p = bp + s * 64;
        br[0] = *(const float4*)p;
        br[1] = *(const float4*)(p + 4);
    };
    auto storeB = [&](const float4 (&br)[2], int buf) {
        uint4 o;
        o.x = pk2bf(br[0].x, br[0].y); o.y = pk2bf(br[0].z, br[0].w);
        o.z = pk2bf(br[1].x, br[1].y); o.w = pk2bf(br[1].z, br[1].w);
        *(uint4*)&Bs[buf][bofs] = o;
    };
    auto loadA = [&](bf16x8 (&af)[3][2], int s) {
        #pragma unroll
        for (int i = 0; i < 3; ++i)
            #pragma unroll
            for (int kk = 0; kk < 2; ++kk)
                af[i][kk] = *(const bf16x8*)(ap[i] + s * 64 + kk * 32);
    };
    auto compute = [&](const bf16x8 (&af)[3][2], int buf) {
        #pragma unroll
        for (int kk = 0; kk < 2; ++kk) {
            const int ko = kk * 32 + quad * 8;
            bf16x8 bg[2], bu[2];
            #pragma unroll
            for (int j = 0; j < 2; ++j) {
                bg[j] = *(const bf16x8*)&Bs[buf][(j * 16 + l16) * BR + ko];
                bu[j] = *(const bf16x8*)&Bs[buf][(32 + j * 16 + l16) * BR + ko];
            }
            #pragma unroll
            for (int i = 0; i < 3; ++i)
                #pragma unroll
                for (int j = 0; j < 2; ++j) {
                    accg[i][j] = __builtin_amdgcn_mfma_f32_16x16x32_bf16(af[i][kk], bg[j], accg[i][j], 0, 0, 0);
                    accu[i][j] = __builtin_amdgcn_mfma_f32_16x16x32_bf16(af[i][kk], bu[j], accu[i][j], 0, 0, 0);
                }
        }
    };

    const int NK = HDIM / 64;   // 32
    loadB(Br0, 0);
    loadA(afA, 0);
    storeB(Br0, 0);
    loadB(Br0, 1);
    loadB(Br1, 2);
    __syncthreads();

    for (int s = 0; s < NK; s += 2) {
        // even half: Bs[s%3]=slab s ready; Br0=raw s+1, Br1=raw s+2
        storeB(Br0, (s + 1) % 3);
        if (s + 3 < NK) loadB(Br0, s + 3);
        loadA(afB, s + 1);
        compute(afA, s % 3);
        __syncthreads();
        // odd half
        if (s + 2 < NK) storeB(Br1, (s + 2) % 3);
        if (s + 4 < NK) loadB(Br1, s + 4);
        if (s + 2 < NK) loadA(afA, s + 2);
        compute(afB, (s + 1) % 3);
        __syncthreads();
    }

    // Epilogue: silu(gate)*up -> inter (packed rows, bf16).
    #pragma unroll
    for (int i = 0; i < 3; ++i) {
        #pragma unroll
        for (int r = 0; r < 4; ++r) {
            int mrow = w * 48 + i * 16 + quad * 4 + r;
            if (mrow < rows && mrow < 384) {
                size_t orow = (size_t)(seg + m0 + mrow) * IDIM;
                #pragma unroll
                for (int j = 0; j < 2; ++j) {
                    float g = accg[i][j][r], u = accu[i][j][r];
                    float sv = g * (1.f / (1.f + __expf(-g)));
                    inter[orow + n0 + j * 16 + l16] = f2bf(sv * u);
                }
            }
        }
    }
}

// ---------------------------------------------------------------------------
// Kernel 3: down-proj GEMM. Same skeleton: 512 thr, full-expert M (384) x 64
// H-cols, B = 64 down rows fp32 streamed once, A = inter direct from L2.
// K-slab 64, NK=16. Output fp32 scattered to out[pairs[p]].
// ---------------------------------------------------------------------------
__global__ __launch_bounds__(512, 2) void gemm2_down(
    const unsigned short* __restrict__ inter, const float* __restrict__ down,
    const int* __restrict__ meta, const int* __restrict__ pairs,
    float* __restrict__ out)
{
    __shared__ __align__(16) unsigned short Bs[3][64 * BR];

    const int bx = blockIdx.x;
    const int e = bx & 7, nt = (bx >> 3) & 31, mt = bx >> 8;
    const int cnt = meta[e];
    const int m0 = mt * 384;
    if (m0 >= cnt) return;
    const int seg  = meta[8 + e];
    const int rows = cnt - m0;
    const int n0   = nt * 64;

    const int tid  = threadIdx.x;
    const int lane = tid & 63, w = tid >> 6;
    const int quad = lane >> 4, l16 = lane & 15;

    const int brow = tid >> 3, bkc = (tid & 7) * 8;
    const float* __restrict__ bp =
        down + (size_t)e * (HDIM * IDIM) + (size_t)(n0 + brow) * IDIM + bkc;
    const int bofs = brow * BR + bkc;

    const unsigned short* ap[3];
    #pragma unroll
    for (int i = 0; i < 3; ++i) {
        int mr  = m0 + w * 48 + i * 16 + l16;
        int idx = seg + min(mr, cnt - 1);
        ap[i] = inter + (size_t)idx * IDIM + quad * 8;
    }

    f32x4 acc[3][4];
    const f32x4 zero = {0.f, 0.f, 0.f, 0.f};
    #pragma unroll
    for (int i = 0; i < 3; ++i)
        #pragma unroll
        for (int j = 0; j < 4; ++j) acc[i][j] = zero;

    float4 Br0[2], Br1[2];
    bf16x8 afA[3][2], afB[3][2];

    auto loadB = [&](float4 (&br)[2], int s) {
        const float* p = bp + s * 64;
        br[0] = *(const float4*)p;
        br[1] = *(const float4*)(p + 4);
    };
    auto storeB = [&](const float4 (&br)[2], int buf) {
        uint4 o;
        o.x = pk2bf(br[0].x, br[0].y); o.y = pk2bf(br[0].z, br[0].w);
        o.z = pk2bf(br[1].x, br[1].y); o.w = pk2bf(br[1].z, br[1].w);
        *(uint4*)&Bs[buf][bofs] = o;
    };
    auto loadA = [&](bf16x8 (&af)[3][2], int s) {
        #pragma unroll
        for (int i = 0; i < 3; ++i)
            #pragma unroll
            for (int kk = 0; kk < 2; ++kk)
                af[i][kk] = *(const bf16x8*)(ap[i] + s * 64 + kk * 32);
    };
    auto compute = [&](const bf16x8 (&af)[3][2], int buf) {
        #pragma unroll
        for (int kk = 0; kk < 2; ++kk) {
            const int ko = kk * 32 + quad * 8;
            bf16x8 bf[4];
            #pragma unroll
            for (int j = 0; j < 4; ++j)
                bf[j] = *(const bf16x8*)&Bs[buf][(j * 16 + l16) * BR + ko];
            #pragma unroll
            for (int i = 0; i < 3; ++i)
                #pragma unroll
                for (int j = 0; j < 4; ++j)
                    acc[i][j] = __builtin_amdgcn_mfma_f32_16x16x32_bf16(af[i][kk], bf[j], acc[i][j], 0, 0, 0);
        }
    };

    const int NK = IDIM / 64;   // 16
    loadB(Br0, 0);
    loadA(afA, 0);
    storeB(Br0, 0);
    loadB(Br0, 1);
    loadB(Br1, 2);
    __syncthreads();

    for (int s = 0; s < NK; s += 2) {
        storeB(Br0, (s + 1) % 3);
        if (s + 3 < NK) loadB(Br0, s + 3);
        loadA(afB, s + 1);
        compute(afA, s % 3);
        __syncthreads();
        if (s + 2 < NK) storeB(Br1, (s + 2) % 3);
        if (s + 4 < NK) loadB(Br1, s + 4);
        if (s + 2 < NK) loadA(afA, s + 2);
        compute(afB, (s + 1) % 3);
        __syncthreads();
    }

    #pragma unroll
    for (int i = 0; i < 3; ++i) {
        #pragma unroll
        for (int r = 0; r < 4; ++r) {
            int mrow = w * 48 + i * 16 + quad * 4 + r;
            if (mrow < rows && mrow < 384) {
                int p = pairs[seg + m0 + mrow];          // == t*K+k = out row
                size_t ob = (size_t)p * HDIM + n0 + l16;
                #pragma unroll
                for (int j = 0; j < 4; ++j)
                    out[ob + j * 16] = acc[i][j][r];
            }
        }
    }
}

// ---------------------------------------------------------------------------
extern "C" void kernel_launch(void* const* d_in, const int* in_sizes, int n_in,
                              void* d_out, int out_size, void* d_ws, size_t ws_size,
                              hipStream_t stream) {
    const float* hidden = (const float*)d_in[0];   // (T, H) fp32
    const int*   sel    = (const int*)  d_in[1];   // (T, K) int32
    const float* gup    = (const float*)d_in[2];   // (E, 2I, H) fp32
    const float* down   = (const float*)d_in[3];   // (E, H, I) fp32
    float* out = (float*)d_out;                    // (T, K, H) fp32

    // ws: meta 16 ints | pairs 2048 ints | inter bf16 2048x1024 (4 MB)
    //     | hid_bf bf16 1024x2048 (4 MB)   -- total ~8.1 MB
    char* ws = (char*)d_ws;
    int* meta  = (int*)ws;
    int* pairs = meta + 16;
    unsigned short* inter  = (unsigned short*)(ws + 16384);
    unsigned short* hid_bf = inter + (size_t)TK * IDIM;

    prep<<<T_TOK * HDIM / 8 / 256, 256, 0, stream>>>(hidden, sel, hid_bf, meta, pairs);
    gemm1_gateup<<<MT * 32 * 8, 512, 0, stream>>>(hid_bf, gup, meta, pairs, inter);
    gemm2_down  <<<MT * 32 * 8, 512, 0, stream>>>(inter, down, meta, pairs, out);
}